// Round 9
// baseline (28.841 us; speedup 1.0000x reference)
//
#include <hip/hip_runtime.h>
#include <hip/hip_bf16.h>

#define NB 128          // tracklets (b)
#define NS 32           // frames per tracklet (s)
#define DF 256          // feature dim
#define NROW (NB*NS)    // 4096
#define KSTEPS (DF/16)  // 16 MFMA k-steps of 16
#define MARGIN 0.3f
#define PANEL (KSTEPS*64)   // bf16x8 slots per tracklet panel
#define NBLK 1056           // rectangular cover: g=0..31, base(g)=65g-g^2, 2 si-rows x (32-g) sj-cols

typedef short bf16x8 __attribute__((ext_vector_type(8)));
typedef short bf16x4 __attribute__((ext_vector_type(4)));
typedef float f32x16 __attribute__((ext_vector_type(16)));

__device__ __forceinline__ short f2bf(float x) {      // RTNE float->bf16 bits
    unsigned u = __float_as_uint(x);
    u += 0x7fffu + ((u >> 16) & 1u);
    return (short)(u >> 16);
}

// ---------------- Kernel 1: normalize -> hi-bf16 fragment tiles ----------------
// Tile layout (per tracklet): slot = (trk*KSTEPS + ks)*64 + lane, 8 bf16 per slot.
// lane l covers frame (l&31), k = ks*16 + (l>>5)*8 + e (same mapping for A and B; Gram-symmetric).
__global__ __launch_bounds__(256) void norm_kernel(const float* __restrict__ in,
                                                   short* __restrict__ Xhi) {
    const int row = blockIdx.x * 4 + (threadIdx.x >> 6);   // 0..4095
    const int lane = threadIdx.x & 63;                     // one float4 each
    const float4 v = ((const float4*)(in + (size_t)row * DF))[lane];
    float s = v.x*v.x + v.y*v.y + v.z*v.z + v.w*v.w;
    #pragma unroll
    for (int off = 32; off; off >>= 1) s += __shfl_xor(s, off);
    const float inv = 1.0f / fmaxf(sqrtf(s), 1e-12f);
    const float o[4] = {v.x*inv, v.y*inv, v.z*inv, v.w*inv};

    const int trk = row >> 5, r32 = row & 31;
    const int k4 = lane * 4;
    const int ks = k4 >> 4;
    const int kq = k4 & 15;
    const int tl = ((kq >> 3) << 5) | r32;
    const size_t off8 = ((size_t)(trk * KSTEPS + ks) * 64 + tl) * 8 + (kq & 7);

    bf16x4 hv;
    #pragma unroll
    for (int c = 0; c < 4; c++) hv[c] = f2bf(o[c]);
    *(bf16x4*)(Xhi + off8) = hv;
}

// -------- Kernel 2: 2x4-tracklet blocks, 2 pairs per wave, dual-direction MFMA --------
// Block covers rows {2si,2si+1} x cols {4sj..4sj+3}: 8 pairs, 6 distinct panels.
// Wave w: i = 2si+(w>>1), j in {4sj+2(w&1), +1} -> 3 frag loads feed 4 MFMA chains/ks.
// Cover: g=si>>1 in 0..31, sj in g..31 (rect cover of triangle). Near-diagonal pairs may
// be computed twice (mirrored operands) -- bitwise-identical results, benign same-value
// stores (mfma(b,a) of the mirror IS this block's accR, combine ops are symmetric).
__global__ __launch_bounds__(256) void pair_kernel(const short* __restrict__ Xhi,
                                                   const int* __restrict__ tgt,
                                                   float* __restrict__ val) {
    const int w = threadIdx.x >> 6;
    const int l = threadIdx.x & 63;
    const int h = l >> 5;
    const int bid = blockIdx.x;                  // 0..1055

    // decode g: largest g with base(g) = 65g - g^2 <= bid
    int g = (int)((65.0f - sqrtf(4225.0f - 4.0f * (float)bid)) * 0.5f);
    while (65 * (g + 1) - (g + 1) * (g + 1) <= bid) ++g;
    while (65 * g - g * g > bid) --g;
    const int rem = bid - (65 * g - g * g);
    const int nsj = 32 - g;
    const int second = (rem >= nsj);
    const int si = 2 * g + second;
    const int sj = g + (second ? rem - nsj : rem);

    const int i  = 2 * si + (w >> 1);
    const int j0 = 4 * sj + 2 * (w & 1);
    const int j1 = j0 + 1;

    const bf16x8* P  = (const bf16x8*)Xhi;
    const bf16x8* A  = P + (size_t)i  * PANEL + l;
    const bf16x8* B0 = P + (size_t)j0 * PANEL + l;
    const bf16x8* B1 = B0 + PANEL;

    f32x16 f0, f1, r0, r1;
    #pragma unroll
    for (int r = 0; r < 16; r++) { f0[r] = 0.0f; f1[r] = 0.0f; r0[r] = 0.0f; r1[r] = 0.0f; }

    #pragma unroll
    for (int ks = 0; ks < KSTEPS; ks++) {
        const bf16x8 a  = A[ks * 64];
        const bf16x8 b0 = B0[ks * 64];
        const bf16x8 b1 = B1[ks * 64];
        f0 = __builtin_amdgcn_mfma_f32_32x32x16_bf16(a, b0, f0, 0, 0, 0);  // cols = j0 frames
        r0 = __builtin_amdgcn_mfma_f32_32x32x16_bf16(b0, a, r0, 0, 0, 0);  // cols = i frames
        f1 = __builtin_amdgcn_mfma_f32_32x32x16_bf16(a, b1, f1, 0, 0, 0);  // cols = j1 frames
        r1 = __builtin_amdgcn_mfma_f32_32x32x16_bf16(b1, a, r1, 0, 0, 0);  // cols = i frames
    }

    const int ti = tgt[i];

    __shared__ float buf[4][64];
    __shared__ float kv[4][2];

    // Acc-domain epilogue: d = sqrt(clip(2-2a)) monotone decreasing =>
    // frame-min(d) <-> colmax(a); K-th largest d <-> K-th smallest a;
    // pos-combine max(d) <-> min(a); neg-combine min(d) <-> max(a).
    auto do_pair = [&](const f32x16& accF, const f32x16& accR, int jj) {
        const bool pos = (ti == tgt[jj]);
        const int K = pos ? 3 : 6;

        float cf = accF[0], cr = accR[0];
        #pragma unroll
        for (int r = 1; r < 16; r++) { cf = fmaxf(cf, accF[r]); cr = fmaxf(cr, accR[r]); }
        cf = fmaxf(cf, __shfl_xor(cf, 32));   // dij candidate, indexed by j-frame (l&31)
        cr = fmaxf(cr, __shfl_xor(cr, 32));   // dji candidate, indexed by i-frame (l&31)

        buf[w][l] = h ? cr : cf;              // [0..31]=ij set, [32..63]=ji set

        const float x = buf[w][l];
        const float* cb = &buf[w][h * 32];
        int c = 0, e = 0;
        #pragma unroll
        for (int q = 0; q < 8; q++) {
            const float4 y = *(const float4*)(cb + 4 * q);
            c += (y.x < x) + (y.y < x) + (y.z < x) + (y.w < x);
            e += (y.x == x) + (y.y == x) + (y.z == x) + (y.w == x);
        }
        if (c < K && c + e >= K) kv[w][h] = x;   // K-th smallest a of this half's 32-set

        if (l == 0) {
            const float aij = kv[w][0], aji = kv[w][1];
            const float ac = pos ? fminf(aij, aji) : fmaxf(aij, aji);
            const float d = sqrtf(fmaxf(2.0f - 2.0f * ac, 1e-12f));
            val[i * NB + jj] = d;
            val[jj * NB + i] = d;
        }
    };
    do_pair(f0, r0, j0);
    do_pair(f1, r1, j1);
}

// ---------------- Kernel 3: fused per-anchor ap/an + margin + mean ----------------
// 1024 threads: 8 lanes per anchor, each lane covers 16 j's via float4 loads.
__global__ __launch_bounds__(1024) void reduce_kernel(const float* __restrict__ val,
                                                      const int* __restrict__ tgt,
                                                      float* __restrict__ out) {
    __shared__ int   tg[NB];
    __shared__ float ls[NB];
    const int tid = threadIdx.x;
    if (tid < NB) tg[tid] = tgt[tid];
    __syncthreads();

    const int i = tid >> 3;     // anchor 0..127
    const int g = tid & 7;      // lane group 0..7
    const int ti = tg[i];
    float ap = -1e30f, an = 1e30f;
    const float4* vp = (const float4*)(val + i * NB + g * 16);
    #pragma unroll
    for (int q = 0; q < 4; q++) {
        const float4 v = vp[q];
        const int jb = g * 16 + q * 4;
        if (tg[jb + 0] == ti) ap = fmaxf(ap, v.x); else an = fminf(an, v.x);
        if (tg[jb + 1] == ti) ap = fmaxf(ap, v.y); else an = fminf(an, v.y);
        if (tg[jb + 2] == ti) ap = fmaxf(ap, v.z); else an = fminf(an, v.z);
        if (tg[jb + 3] == ti) ap = fmaxf(ap, v.w); else an = fminf(an, v.w);
    }
    #pragma unroll
    for (int off = 1; off < 8; off <<= 1) {
        ap = fmaxf(ap, __shfl_xor(ap, off));
        an = fminf(an, __shfl_xor(an, off));
    }
    if (g == 0) ls[i] = fmaxf(ap - an + MARGIN, 0.0f);
    __syncthreads();

    if (tid < 64) {
        float li = ls[tid] + ls[tid + 64];
        #pragma unroll
        for (int off = 32; off; off >>= 1) li += __shfl_xor(li, off);
        if (tid == 0) out[0] = li * (1.0f / (float)NB);
    }
}

extern "C" void kernel_launch(void* const* d_in, const int* in_sizes, int n_in,
                              void* d_out, int out_size, void* d_ws, size_t ws_size,
                              hipStream_t stream) {
    const float* in = (const float*)d_in[0];   // (128,32,256) f32
    const int* tgt = (const int*)d_in[1];      // (128,) i32
    float* out = (float*)d_out;                // scalar

    short* Xhi = (short*)d_ws;                           // 4096*256 bf16 (2 MB)
    float* val = (float*)(Xhi + (size_t)NROW * DF);      // 16384 floats

    norm_kernel<<<NROW / 4, 256, 0, stream>>>(in, Xhi);
    pair_kernel<<<NBLK, 256, 0, stream>>>(Xhi, tgt, val);
    reduce_kernel<<<1, 1024, 0, stream>>>(val, tgt, out);
}

// Round 10
// 25.285 us; speedup vs baseline: 1.1407x; 1.1407x over previous
//
#include <hip/hip_runtime.h>
#include <hip/hip_bf16.h>

#define NB 128          // tracklets (b)
#define NS 32           // frames per tracklet (s)
#define DF 256          // feature dim
#define NROW (NB*NS)    // 4096
#define KSTEPS (DF/16)  // 16 MFMA k-steps of 16
#define MARGIN 0.3f
#define PANEL (KSTEPS*64)       // bf16x8 slots per tracklet panel
#define NSUP (NB/2)             // 64 super-tracklets (2x2 pair tiles)
#define NSBLK (NSUP*(NSUP+1)/2) // 2080 blocks over super upper-triangle

typedef short bf16x8 __attribute__((ext_vector_type(8)));
typedef short bf16x4 __attribute__((ext_vector_type(4)));
typedef float f32x16 __attribute__((ext_vector_type(16)));

__device__ __forceinline__ short f2bf(float x) {      // RTNE float->bf16 bits
    unsigned u = __float_as_uint(x);
    u += 0x7fffu + ((u >> 16) & 1u);
    return (short)(u >> 16);
}

// ---------------- Kernel 1: normalize -> hi-bf16 fragment tiles ----------------
// Tile layout (per tracklet): slot = (trk*KSTEPS + ks)*64 + lane, 8 bf16 per slot.
// lane l covers frame (l&31), k = ks*16 + (l>>5)*8 + e (same mapping for A and B; Gram-symmetric).
__global__ __launch_bounds__(256) void norm_kernel(const float* __restrict__ in,
                                                   short* __restrict__ Xhi) {
    const int row = blockIdx.x * 4 + (threadIdx.x >> 6);   // 0..4095
    const int lane = threadIdx.x & 63;                     // one float4 each
    const float4 v = ((const float4*)(in + (size_t)row * DF))[lane];
    float s = v.x*v.x + v.y*v.y + v.z*v.z + v.w*v.w;
    #pragma unroll
    for (int off = 32; off; off >>= 1) s += __shfl_xor(s, off);
    const float inv = 1.0f / fmaxf(sqrtf(s), 1e-12f);
    const float o[4] = {v.x*inv, v.y*inv, v.z*inv, v.w*inv};

    const int trk = row >> 5, r32 = row & 31;
    const int k4 = lane * 4;
    const int ks = k4 >> 4;
    const int kq = k4 & 15;
    const int tl = ((kq >> 3) << 5) | r32;
    const size_t off8 = ((size_t)(trk * KSTEPS + ks) * 64 + tl) * 8 + (kq & 7);

    bf16x4 hv;
    #pragma unroll
    for (int c = 0; c < 4; c++) hv[c] = f2bf(o[c]);
    *(bf16x4*)(Xhi + off8) = hv;
}

// ------------- Kernel 2: 2x2 super-tile pair blocks, dual-direction MFMA -------------
// 4 waves/block compute pairs (2si+{0,1}, 2sj+{0,1}) -> each panel shared by 2 waves
// via L1. val symmetric: compute si<=sj only, write both (i,j) and (j,i). Diagonal
// supers produce benign bitwise-identical duplicate pair computations.
__global__ __launch_bounds__(256) void pair_kernel(const short* __restrict__ Xhi,
                                                   const int* __restrict__ tgt,
                                                   float* __restrict__ val) {
    const int w = threadIdx.x >> 6;
    const int l = threadIdx.x & 63;
    const int h = l >> 5;
    const int sidx = blockIdx.x;                 // 0..2079

    // triangular decode over supers: largest si with si*NSUP - si*(si-1)/2 <= sidx
    int si = (int)(64.5f - sqrtf(64.5f * 64.5f - 2.0f * (float)sidx));
    while ((si + 1) * NSUP - ((si + 1) * si) / 2 <= sidx) ++si;
    while (si * NSUP - (si * (si - 1)) / 2 > sidx) --si;
    const int sj = si + (sidx - (si * NSUP - (si * (si - 1)) / 2));
    const int i = 2 * si + (w >> 1);
    const int j = 2 * sj + (w & 1);

    const bf16x8* P = (const bf16x8*)Xhi;
    const bf16x8* A = P + (size_t)i * PANEL + l;
    const bf16x8* B = P + (size_t)j * PANEL + l;

    f32x16 accF, accR;
    #pragma unroll
    for (int r = 0; r < 16; r++) { accF[r] = 0.0f; accR[r] = 0.0f; }

    #pragma unroll
    for (int ks = 0; ks < KSTEPS; ks++) {
        const bf16x8 a = A[ks * 64];
        const bf16x8 b = B[ks * 64];
        accF = __builtin_amdgcn_mfma_f32_32x32x16_bf16(a, b, accF, 0, 0, 0);  // cols = j frames
        accR = __builtin_amdgcn_mfma_f32_32x32x16_bf16(b, a, accR, 0, 0, 0);  // cols = i frames
    }

    // Acc-domain epilogue: d = sqrt(clip(2-2a)) monotone decreasing =>
    // frame-min(d) <-> colmax(a); K-th largest d <-> K-th smallest a;
    // pos-combine max(d) <-> min(a); neg-combine min(d) <-> max(a).
    const bool pos = (tgt[i] == tgt[j]);
    const int K = pos ? 3 : 6;

    float cf = accF[0], cr = accR[0];
    #pragma unroll
    for (int r = 1; r < 16; r++) { cf = fmaxf(cf, accF[r]); cr = fmaxf(cr, accR[r]); }
    cf = fmaxf(cf, __shfl_xor(cf, 32));   // dij candidate, indexed by j-frame (l&31)
    cr = fmaxf(cr, __shfl_xor(cr, 32));   // dji candidate, indexed by i-frame (l&31)

    __shared__ float buf[4][64];
    __shared__ float kv[4][2];
    buf[w][l] = h ? cr : cf;              // [0..31]=ij set, [32..63]=ji set

    const float x = buf[w][l];
    const float* cb = &buf[w][h * 32];
    int c = 0, e = 0;
    #pragma unroll
    for (int q = 0; q < 8; q++) {
        const float4 y = *(const float4*)(cb + 4 * q);
        c += (y.x < x) + (y.y < x) + (y.z < x) + (y.w < x);
        e += (y.x == x) + (y.y == x) + (y.z == x) + (y.w == x);
    }
    if (c < K && c + e >= K) kv[w][h] = x;   // K-th smallest a of this half's 32-set

    if (l == 0) {
        const float aij = kv[w][0], aji = kv[w][1];
        const float ac = pos ? fminf(aij, aji) : fmaxf(aij, aji);
        const float d = sqrtf(fmaxf(2.0f - 2.0f * ac, 1e-12f));
        val[i * NB + j] = d;
        val[j * NB + i] = d;
    }
}

// ---------------- Kernel 3: fused per-anchor ap/an + margin + mean ----------------
// 1024 threads: 8 lanes per anchor, each lane covers 16 j's via float4 loads.
__global__ __launch_bounds__(1024) void reduce_kernel(const float* __restrict__ val,
                                                      const int* __restrict__ tgt,
                                                      float* __restrict__ out) {
    __shared__ int   tg[NB];
    __shared__ float ls[NB];
    const int tid = threadIdx.x;
    if (tid < NB) tg[tid] = tgt[tid];
    __syncthreads();

    const int i = tid >> 3;     // anchor 0..127
    const int g = tid & 7;      // lane group 0..7
    const int ti = tg[i];
    float ap = -1e30f, an = 1e30f;
    const float4* vp = (const float4*)(val + i * NB + g * 16);
    #pragma unroll
    for (int q = 0; q < 4; q++) {
        const float4 v = vp[q];
        const int jb = g * 16 + q * 4;
        if (tg[jb + 0] == ti) ap = fmaxf(ap, v.x); else an = fminf(an, v.x);
        if (tg[jb + 1] == ti) ap = fmaxf(ap, v.y); else an = fminf(an, v.y);
        if (tg[jb + 2] == ti) ap = fmaxf(ap, v.z); else an = fminf(an, v.z);
        if (tg[jb + 3] == ti) ap = fmaxf(ap, v.w); else an = fminf(an, v.w);
    }
    #pragma unroll
    for (int off = 1; off < 8; off <<= 1) {
        ap = fmaxf(ap, __shfl_xor(ap, off));
        an = fminf(an, __shfl_xor(an, off));
    }
    if (g == 0) ls[i] = fmaxf(ap - an + MARGIN, 0.0f);
    __syncthreads();

    if (tid < 64) {
        float li = ls[tid] + ls[tid + 64];
        #pragma unroll
        for (int off = 32; off; off >>= 1) li += __shfl_xor(li, off);
        if (tid == 0) out[0] = li * (1.0f / (float)NB);
    }
}

extern "C" void kernel_launch(void* const* d_in, const int* in_sizes, int n_in,
                              void* d_out, int out_size, void* d_ws, size_t ws_size,
                              hipStream_t stream) {
    const float* in = (const float*)d_in[0];   // (128,32,256) f32
    const int* tgt = (const int*)d_in[1];      // (128,) i32
    float* out = (float*)d_out;                // scalar

    short* Xhi = (short*)d_ws;                           // 4096*256 bf16 (2 MB)
    float* val = (float*)(Xhi + (size_t)NROW * DF);      // 16384 floats

    norm_kernel<<<NROW / 4, 256, 0, stream>>>(in, Xhi);
    pair_kernel<<<NSBLK, 256, 0, stream>>>(Xhi, tgt, val);
    reduce_kernel<<<1, 1024, 0, stream>>>(val, tgt, out);
}